// Round 22
// baseline (1262.597 us; speedup 1.0000x reference)
//
#include <hip/hip_runtime.h>
#include <math.h>

#define BATCH 16
#define CIN   128
#define HH    192
#define WW    192
#define HW    (HH*WW)
#define OC    64
#define KPTS  512
#define CAP   2048
#define UMAX  (CAP*9)
#define LBLK  768     // logit slots per batch
#define PPB   8       // pixels per logit tile
#define NXB   (HW/64) // 576 xq blocks per batch

typedef short short8 __attribute__((ext_vector_type(8)));
typedef float f32x4 __attribute__((ext_vector_type(4)));

__device__ __forceinline__ unsigned short rne_bf16(float v) {
  unsigned u = __float_as_uint(v);
  u += 0x7FFFu + ((u >> 16) & 1u);
  return (unsigned short)(u >> 16);
}

// --- K1: transpose feat -> xq [bl][hw][c] raw f32 + per-block channel partial sums ---
__global__ __launch_bounds__(256) void xq_kernel(const float* __restrict__ feat,
                                                 float* __restrict__ xq,
                                                 double* __restrict__ psum,
                                                 int b0) {
  __shared__ float lds[64*130];                 // [px][c], pad 130
  const int bl = blockIdx.y;
  const int b  = b0 + bl;
  const int px0 = blockIdx.x * 64;
  const int tid = threadIdx.x;
  const int lane = tid & 63, wq = tid >> 6;

  #pragma unroll 8
  for (int k = 0; k < 32; k++) {
    int c = wq + 4*k;
    lds[lane*130 + c] = feat[((size_t)(b*CIN + c))*HW + px0 + lane];
  }
  __syncthreads();

  if (tid < CIN) {
    double s = 0.0;
    #pragma unroll 8
    for (int px = 0; px < 64; px++) s += (double)lds[px*130 + tid];
    psum[((size_t)b*CIN + tid)*NXB + blockIdx.x] = s;
  }

  const int px = tid >> 2, cq = tid & 3;
  size_t base = ((size_t)bl*HW + px0 + px)*CIN + cq*32;
  float4* xqp = (float4*)(xq + base);
  #pragma unroll
  for (int half = 0; half < 8; half++) {
    float4 q;
    #pragma unroll
    for (int j = 0; j < 4; j++)
      ((float*)&q)[j] = lds[px*130 + cq*32 + half*4 + j];
    xqp[half] = q;
  }
}

// --- K1b: reduce psum -> pool (f64, fixed order) ---
__global__ __launch_bounds__(64) void poolreduce_kernel(const double* __restrict__ psum,
                                                        double* __restrict__ pool,
                                                        int b0) {
  const int lb = blockIdx.x / CIN, c = blockIdx.x % CIN;
  const int b = b0 + lb;
  const int tid = threadIdx.x;
  const double* pp = psum + ((size_t)b*CIN + c)*NXB;
  double s = 0.0;
  for (int j = tid; j < NXB; j += 64) s += pp[j];
  for (int off = 32; off > 0; off >>= 1) s += __shfl_down(s, off, 64);
  if (tid == 0) pool[b*CIN + c] = s / 36864.0;
}

// ---------------- K2: attn = sigmoid(pool @ attn_w.T + attn_b) ----------------
__global__ __launch_bounds__(128) void attn_kernel(const double* __restrict__ pool,
                                                   const float* __restrict__ attn_w,
                                                   const float* __restrict__ attn_b,
                                                   double* __restrict__ attn_d,
                                                   float* __restrict__ attn_f,
                                                   int b0) {
  __shared__ double sp[CIN];
  int b = b0 + blockIdx.x, c = threadIdx.x;
  sp[c] = pool[b*CIN + c];
  __syncthreads();
  double s = (double)attn_b[c];
  const float* wr = attn_w + (size_t)c * CIN;
  for (int j = 0; j < CIN; j++) s = fma((double)wr[j], sp[j], s);
  double a = 1.0 / (1.0 + exp(-s));
  attn_d[b*CIN + c] = a;
  attn_f[b*CIN + c] = (float)a;
}

// --- K2b: shared split-bf16 wb [tap][oc][c] for the conv ---
__global__ __launch_bounds__(256) void wtrans_kernel(const float* __restrict__ w,
                                                     unsigned short* __restrict__ wb_h,
                                                     unsigned short* __restrict__ wb_l) {
  int i = blockIdx.x * 256 + threadIdx.x;
  if (i < OC*CIN*9) {
    int oc = i / (CIN*9);
    int r  = i % (CIN*9);
    int c  = r / 9;
    int k  = r % 9;
    float v = w[i];
    unsigned short h = rne_bf16(v);
    float hf = __uint_as_float((unsigned)h << 16);
    wb_h[((size_t)k*OC + oc)*CIN + c] = h;
    wb_l[((size_t)k*OC + oc)*CIN + c] = rne_bf16(v - hf);
  }
}

// --- K2c: per-batch f64 attn-folded refine weights wab64p[b][c][oc][10] (pad=0) ---
__global__ __launch_bounds__(256) void wscale64_kernel(const float* __restrict__ w,
                                                       const double* __restrict__ attn_d,
                                                       double* __restrict__ wab64p,
                                                       int b0) {
  const int b = b0 + blockIdx.y;
  int i = blockIdx.x * 256 + threadIdx.x;   // i over CIN*OC*10
  if (i < CIN*OC*10) {
    int kk = i % 10;
    int co = i / 10;
    int oc = co & 63, c = co >> 6;
    double v = 0.0;
    if (kk < 9) v = (double)w[((size_t)oc*CIN + c)*9 + kk] * attn_d[b*CIN + c];
    wab64p[(((size_t)b*CIN + c)*OC + oc)*10 + kk] = v;
  }
}

// ---- conv helpers: per-element convert (bit-identical to prior in-stage math) ----
__device__ __forceinline__ void cvt1(float raw, float a,
                                     unsigned short &h, unsigned short &l) {
  float v = raw * a;
  h = rne_bf16(v);
  l = rne_bf16(v - __uint_as_float((unsigned)h << 16));
}

__device__ __forceinline__ void cvt_store(float4 A, float4 B, const float* at,
                                          unsigned short* thp, unsigned short* tlp) {
  short8 hv, lv; unsigned short h, l;
  cvt1(A.x, at[0], h, l); hv[0]=(short)h; lv[0]=(short)l;
  cvt1(A.y, at[1], h, l); hv[1]=(short)h; lv[1]=(short)l;
  cvt1(A.z, at[2], h, l); hv[2]=(short)h; lv[2]=(short)l;
  cvt1(A.w, at[3], h, l); hv[3]=(short)h; lv[3]=(short)l;
  cvt1(B.x, at[4], h, l); hv[4]=(short)h; lv[4]=(short)l;
  cvt1(B.y, at[5], h, l); hv[5]=(short)h; lv[5]=(short)l;
  cvt1(B.z, at[6], h, l); hv[6]=(short)h; lv[6]=(short)l;
  cvt1(B.w, at[7], h, l); hv[7]=(short)h; lv[7]=(short)l;
  *reinterpret_cast<short8*>(thp) = hv;
  *reinterpret_cast<short8*>(tlp) = lv;
}

__device__ __forceinline__ void load_cvt_store(bool val, const float* up, int c0,
                                               const float* at,
                                               unsigned short* thp, unsigned short* tlp) {
  const float4 zf = (float4){0.f, 0.f, 0.f, 0.f};
  float4 A = zf, B = zf;
  if (val) {
    A = *(const float4*)(up + c0);
    B = *(const float4*)(up + c0 + 4);
  }
  cvt_store(A, B, at, thp, tlp);
}

// -------- K3: split-bf16 MFMA conv; named-register prefetch of stage units 0-2 --------
#define TLH 18
#define TLW 18
#define CST 36
__global__ __launch_bounds__(256, 3) void conv_kernel(const float* __restrict__ xq,
                                                      const float* __restrict__ attn_f,
                                                      const unsigned short* __restrict__ wb_h,
                                                      const unsigned short* __restrict__ wb_l,
                                                      const float* __restrict__ conv1_b,
                                                      const float* __restrict__ conv2_w,
                                                      const float* __restrict__ conv2_b,
                                                      float* __restrict__ depth_out,
                                                      float* __restrict__ logit_out,
                                                      int b0, int nwg) {
  // bijective XCD swizzle (m204): nwg = g*144
  int bid = blockIdx.x;
  int q = nwg >> 3, r = nwg & 7;
  int xcd = bid & 7, pos = bid >> 3;
  int swz = (xcd < r ? xcd*(q+1) : r*(q+1) + (xcd - r)*q) + pos;
  const int bl = swz / 144;
  const int t144 = swz % 144;
  const int b  = b0 + bl;
  const int h0 = (t144 / 12) * 16, w0 = (t144 % 12) * 16;
  const int tid = threadIdx.x;
  const int wv = tid >> 6, ln = tid & 63;
  const int lg = ln >> 4, lr = ln & 15;

  __shared__ __align__(16) unsigned short th[TLH*TLW*CST];  // 23328 B
  __shared__ __align__(16) unsigned short tl[TLH*TLW*CST];  // 23328 B
  __shared__ float s_attn[CIN];

  if (tid < CIN) s_attn[tid] = attn_f[b*CIN + tid];

  // per-unit constants (i = tid + n*256); units 0..4 always index-valid, 5 iff tid<16
#define UNITDEF(n, ioff)                                                     \
  const int i##n = tid + (ioff);                                             \
  const int rr##n = i##n / (TLW*4), rw##n = i##n % (TLW*4);                  \
  const int col##n = rw##n >> 2, s##n = (rw##n & 3) * 8;                     \
  const int gh##n = h0 + rr##n - 1, gw##n = w0 + col##n - 1;                 \
  const bool val##n = (gh##n >= 0) && (gh##n < HH) && (gw##n >= 0) && (gw##n < WW); \
  const float* up##n = xq + ((size_t)(bl*HH + gh##n)*WW + gw##n)*CIN + s##n; \
  const int o##n = (rr##n*TLW + col##n)*CST + s##n;

  UNITDEF(0, 0)
  UNITDEF(1, 256)
  UNITDEF(2, 512)
  UNITDEF(3, 768)
  UNITDEF(4, 1024)
  UNITDEF(5, 1280)
#undef UNITDEF
  const bool u5ok = (i5 < TLH*TLW*4);

  f32x4 acc[4][4];
  #pragma unroll
  for (int mi = 0; mi < 4; mi++)
    #pragma unroll
    for (int ni = 0; ni < 4; ni++)
      acc[mi][ni] = (f32x4){0.f, 0.f, 0.f, 0.f};

  const float4 zf = (float4){0.f, 0.f, 0.f, 0.f};
  float4 pa0, pb0, pa1, pb1, pa2, pb2;

#define ISSUE(c0v)                                                           \
  pa0 = val0 ? *(const float4*)(up0 + (c0v))     : zf;                       \
  pb0 = val0 ? *(const float4*)(up0 + (c0v) + 4) : zf;                       \
  pa1 = val1 ? *(const float4*)(up1 + (c0v))     : zf;                       \
  pb1 = val1 ? *(const float4*)(up1 + (c0v) + 4) : zf;                       \
  pa2 = val2 ? *(const float4*)(up2 + (c0v))     : zf;                       \
  pb2 = val2 ? *(const float4*)(up2 + (c0v) + 4) : zf;

  ISSUE(0)

  #pragma unroll 1
  for (int c0 = 0; c0 < CIN; c0 += 32) {
    __syncthreads();
    // convert prefetched units 0-2 from registers; units 3-5 synchronous
    cvt_store(pa0, pb0, &s_attn[c0 + s0], &th[o0], &tl[o0]);
    cvt_store(pa1, pb1, &s_attn[c0 + s1], &th[o1], &tl[o1]);
    cvt_store(pa2, pb2, &s_attn[c0 + s2], &th[o2], &tl[o2]);
    load_cvt_store(val3, up3, c0, &s_attn[c0 + s3], &th[o3], &tl[o3]);
    load_cvt_store(val4, up4, c0, &s_attn[c0 + s4], &th[o4], &tl[o4]);
    if (u5ok)
      load_cvt_store(val5, up5, c0, &s_attn[c0 + s5], &th[o5], &tl[o5]);
    __syncthreads();

    if (c0 + 32 < CIN) { ISSUE(c0 + 32) }   // loads fly under the MFMA phase

    #pragma unroll
    for (int v = 0; v < 3; v++) {
      short8 ah[6], al[6];
      #pragma unroll
      for (int r6 = 0; r6 < 6; r6++) {
        int off = ((4*wv + r6)*TLW + lr + v)*CST + 8*lg;
        ah[r6] = *reinterpret_cast<const short8*>(&th[off]);
        al[r6] = *reinterpret_cast<const short8*>(&tl[off]);
      }
      #pragma unroll
      for (int u = 0; u < 3; u++) {
        short8 bh[4], blo[4];
        #pragma unroll
        for (int ni = 0; ni < 4; ni++) {
          size_t woff = ((size_t)(u*3 + v)*OC + ni*16 + lr)*CIN + c0 + 8*lg;
          bh[ni]  = *reinterpret_cast<const short8*>(wb_h + woff);
          blo[ni] = *reinterpret_cast<const short8*>(wb_l + woff);
        }
        #pragma unroll
        for (int mi = 0; mi < 4; mi++) {
          #pragma unroll
          for (int ni = 0; ni < 4; ni++) {
            acc[mi][ni] = __builtin_amdgcn_mfma_f32_16x16x32_bf16(ah[mi+u], bh[ni],  acc[mi][ni], 0, 0, 0);
            acc[mi][ni] = __builtin_amdgcn_mfma_f32_16x16x32_bf16(ah[mi+u], blo[ni], acc[mi][ni], 0, 0, 0);
            acc[mi][ni] = __builtin_amdgcn_mfma_f32_16x16x32_bf16(al[mi+u], bh[ni],  acc[mi][ni], 0, 0, 0);
          }
        }
      }
    }
  }
#undef ISSUE

  float bia[4], w20[4], w21[4];
  #pragma unroll
  for (int ni = 0; ni < 4; ni++) {
    int oc = ni*16 + lr;
    bia[ni] = conv1_b[oc];
    w20[ni] = conv2_w[oc];
    w21[ni] = conv2_w[OC + oc];
  }
  const float c2b0 = conv2_b[0], c2b1 = conv2_b[1];

  #pragma unroll
  for (int mi = 0; mi < 4; mi++) {
    const int gh = h0 + 4*wv + mi;
    #pragma unroll
    for (int q2 = 0; q2 < 4; q2++) {
      float s0v = 0.f, s1v = 0.f;
      #pragma unroll
      for (int ni = 0; ni < 4; ni++) {
        float z = acc[mi][ni][q2] + bia[ni];
        float g = 0.5f * z * (1.0f + erff(z * 0.70710678118654752f));
        s0v = fmaf(g, w20[ni], s0v);
        s1v = fmaf(g, w21[ni], s1v);
      }
      #pragma unroll
      for (int m = 1; m <= 8; m <<= 1) {
        s0v += __shfl_xor(s0v, m, 64);
        s1v += __shfl_xor(s1v, m, 64);
      }
      if (lr == 0) {
        const int gw = w0 + 4*lg + q2;
        depth_out[((size_t)b*HH + gh)*WW + gw] = s0v + c2b0;
        logit_out[((size_t)b*HH + gh)*WW + gw] = s1v + c2b1;
      }
    }
  }
}

// ---------------- K4: per-batch softmax over HW (fp32, in place) + save max ----------------
__global__ __launch_bounds__(1024) void softmax_kernel(float* __restrict__ logits,
                                                       float* __restrict__ m_out,
                                                       int b0) {
  const int b = b0 + blockIdx.x;
  float* lp = logits + (size_t)b * HW;
  const int tid = threadIdx.x;
  __shared__ float sred[16];
  __shared__ float s_m, s_z;

  float m = -INFINITY;
  for (int i = tid; i < HW; i += 1024) m = fmaxf(m, lp[i]);
  for (int off = 32; off > 0; off >>= 1) m = fmaxf(m, __shfl_down(m, off, 64));
  if ((tid & 63) == 0) sred[tid >> 6] = m;
  __syncthreads();
  if (tid == 0) {
    float t = sred[0];
    for (int i = 1; i < 16; i++) t = fmaxf(t, sred[i]);
    s_m = t;
    m_out[b] = t;
  }
  __syncthreads();
  m = s_m;

  float z = 0.f;
  for (int i = tid; i < HW; i += 1024) z += expf(lp[i] - m);
  __syncthreads();
  for (int off = 32; off > 0; off >>= 1) z += __shfl_down(z, off, 64);
  if ((tid & 63) == 0) sred[tid >> 6] = z;
  __syncthreads();
  if (tid == 0) {
    float t = 0.f;
    for (int i = 0; i < 16; i++) t += sred[i];
    s_z = t;
  }
  __syncthreads();
  z = s_z;

  for (int i = tid; i < HW; i += 1024) lp[i] = expf(lp[i] - m) / z;
}

// ---------------- K5: 3x3 box filter (zero pad) / 9, fp32 ----------------
__global__ __launch_bounds__(256) void box_kernel(const float* __restrict__ p,
                                                  float* __restrict__ out_f,
                                                  int b0, int g) {
  int i = blockIdx.x * 256 + threadIdx.x;
  if (i >= g * HW) return;
  int b = b0 + i / HW, r = i % HW, h = r / WW, w = r % WW;
  const float* bp = p + (size_t)b * HW;
  float s = 0.f;
  for (int dy = -1; dy <= 1; dy++) {
    int h2 = h + dy;
    if (h2 < 0 || h2 >= HH) continue;
    for (int dx = -1; dx <= 1; dx++) {
      int w2 = w + dx;
      if (w2 < 0 || w2 >= WW) continue;
      s += bp[h2*WW + w2];
    }
  }
  out_f[(size_t)b*HW + r] = s / 9.0f;
}

// ---------------- K6: candidates (margin 1e-4) + union-of-neighborhood list ----------------
__global__ __launch_bounds__(1024) void cand_kernel(const float* __restrict__ conf,
                                                    int* __restrict__ cand_idx,
                                                    int* __restrict__ cand_cnt,
                                                    int* __restrict__ upix,
                                                    int* __restrict__ upix_cnt,
                                                    int b0) {
  const int b = b0 + blockIdx.x;
  const float* cp = conf + (size_t)b * HW;
  const int tid = threadIdx.x;
  __shared__ unsigned sred[16];
  __shared__ unsigned s_total;
  __shared__ unsigned s_cnt;
  __shared__ unsigned bm[1152];     // 36864-bit map
  __shared__ unsigned pcs[1152];
  __shared__ unsigned grpoff[37];

  unsigned lo = 0u, hi = 0x7F800000u;   // conf > 0 always
  while (hi - lo > 1u) {
    unsigned mid = lo + ((hi - lo) >> 1);
    unsigned cnt = 0;
    for (int i = tid; i < HW; i += 1024)
      cnt += (__float_as_uint(cp[i]) >= mid) ? 1u : 0u;
    for (int off = 32; off > 0; off >>= 1) cnt += __shfl_down(cnt, off, 64);
    if ((tid & 63) == 0) sred[tid >> 6] = cnt;
    __syncthreads();
    if (tid == 0) {
      unsigned t = 0;
      for (int i = 0; i < 16; i++) t += sred[i];
      s_total = t;
    }
    __syncthreads();
    unsigned total = s_total;
    __syncthreads();
    if (total >= KPTS) lo = mid; else hi = mid;
  }
  float vcut = __uint_as_float(lo) * (1.0f - 1e-4f);  // fp32-path conf err ~2e-6 rel

  if (tid == 0) s_cnt = 0;
  for (int i = tid; i < 1152; i += 1024) bm[i] = 0u;
  __syncthreads();

  for (int i = tid; i < HW; i += 1024) {
    if (cp[i] >= vcut) {
      unsigned s = atomicAdd(&s_cnt, 1u);
      if (s < CAP) {
        cand_idx[b*CAP + s] = i;
        int h = i / WW, w = i % WW;
        for (int dy = -1; dy <= 1; dy++) {
          int qh = h + dy;
          if (qh < 0 || qh >= HH) continue;
          for (int dx = -1; dx <= 1; dx++) {
            int qw = w + dx;
            if (qw < 0 || qw >= WW) continue;
            int q = qh*WW + qw;
            atomicOr(&bm[q >> 5], 1u << (q & 31));
          }
        }
      }
    }
  }
  __syncthreads();
  if (tid == 0) cand_cnt[b] = (s_cnt < CAP) ? s_cnt : CAP;

  for (int i = tid; i < 1152; i += 1024) pcs[i] = __popc(bm[i]);
  __syncthreads();
  if (tid < 36) {
    unsigned s = 0;
    for (int j = 0; j < 32; j++) s += pcs[tid*32 + j];
    grpoff[tid] = s;
  }
  __syncthreads();
  if (tid == 0) {
    unsigned run = 0;
    for (int g2 = 0; g2 < 36; g2++) { unsigned t = grpoff[g2]; grpoff[g2] = run; run += t; }
    grpoff[36] = run;
    upix_cnt[b] = (int)run;
  }
  __syncthreads();
  for (int i = tid; i < 1152; i += 1024) {
    unsigned off = grpoff[i >> 5];
    for (int w = (i & ~31); w < i; w++) off += pcs[w];
    unsigned u = bm[i];
    while (u) {
      int bit = __ffs(u) - 1;
      u &= u - 1u;
      upix[b*UMAX + off++] = i*32 + bit;
    }
  }
}

// ------- K7a: f64 logit; PPB=8/tile; x gathered from xq (channel-fastest, coalesced) -------
__global__ __launch_bounds__(256) void logit_kernel(const float* __restrict__ xq,
                                                    const double* __restrict__ wab64p,
                                                    const float* __restrict__ conv1_b,
                                                    const float* __restrict__ conv2_w,
                                                    const float* __restrict__ conv2_b,
                                                    const int* __restrict__ upix,
                                                    const int* __restrict__ upix_cnt,
                                                    double* __restrict__ lmap,
                                                    int b0, int nb) {
  // bijective chunked XCD swizzle (nb = g*LBLK, % 8 == 0)
  int bid = blockIdx.x;
  int swz = (bid & 7) * (nb >> 3) + (bid >> 3);
  const int bl = swz / LBLK;            // local batch in group
  const int b  = b0 + bl;
  const int slot0 = swz % LBLK;
  const int ucnt = upix_cnt[b];
  const int tid = threadIdx.x;

  __shared__ __align__(16) float xf[PPB][1536];   // 48 KB : f32 x, channel stride 12
  __shared__ double part[4][PPB][64];             // 16 KB  [cq][p][oc]
  __shared__ int    s_pix[PPB];

  for (int base = slot0*PPB; base < ucnt; base += LBLK*PPB) {
    const int rem = min(PPB, ucnt - base);
    if (tid < PPB) s_pix[tid] = (tid < rem) ? upix[b*UMAX + base + tid] : 0;
    __syncthreads();

    for (int i = tid; i < PPB*9*32; i += 256) {
      int p = i / 288;
      int r = i % 288;
      int k = r >> 5, t = r & 31;
      float4 v = (float4){0.f, 0.f, 0.f, 0.f};
      if (p < rem) {
        int pix = s_pix[p];
        int gh = pix / WW + k/3 - 1, gw = pix % WW + k%3 - 1;
        if (gh >= 0 && gh < HH && gw >= 0 && gw < WW)
          v = *reinterpret_cast<const float4*>(
                xq + ((size_t)(bl*HW + gh*WW + gw))*CIN + 4*t);
      }
      int cb = 4*t;
      xf[p][(cb+0)*12 + k] = v.x;
      xf[p][(cb+1)*12 + k] = v.y;
      xf[p][(cb+2)*12 + k] = v.z;
      xf[p][(cb+3)*12 + k] = v.w;
    }
    __syncthreads();

    const int oc = tid & 63, cq = tid >> 6;
    double acc[PPB];
    #pragma unroll
    for (int p = 0; p < PPB; p++) acc[p] = 0.0;
    const double* wp = wab64p + (((size_t)b*CIN + cq*32)*OC + oc)*10;
    for (int cc = 0; cc < 32; cc++) {
      const int c = cq*32 + cc;
      double2 wv[5];
      #pragma unroll
      for (int q = 0; q < 5; q++) wv[q] = *((const double2*)wp + q);
      wp += OC*10;
      #pragma unroll
      for (int p = 0; p < PPB; p++) {
        const float4* xp = (const float4*)&xf[p][c*12];
        float4 a = xp[0], bb = xp[1], cc4 = xp[2];
        double t = acc[p];
        t = fma(wv[0].x, (double)a.x,  t);
        t = fma(wv[0].y, (double)a.y,  t);
        t = fma(wv[1].x, (double)a.z,  t);
        t = fma(wv[1].y, (double)a.w,  t);
        t = fma(wv[2].x, (double)bb.x, t);
        t = fma(wv[2].y, (double)bb.y, t);
        t = fma(wv[3].x, (double)bb.z, t);
        t = fma(wv[3].y, (double)bb.w, t);
        t = fma(wv[4].x, (double)cc4.x, t);
        acc[p] = t;
      }
    }
    #pragma unroll
    for (int p = 0; p < PPB; p++) part[cq][p][oc] = acc[p];
    __syncthreads();

    for (int t0 = tid; t0 < PPB*64; t0 += 256) {
      const int p = t0 >> 6, o = t0 & 63;
      double z = part[0][p][o] + part[1][p][o] + part[2][p][o] + part[3][p][o]
               + (double)conv1_b[o];
      double g = 0.5 * z * (1.0 + erf(z * 0.70710678118654752440));
      double cv = g * (double)conv2_w[OC + o];
      #pragma unroll
      for (int m = 1; m <= 32; m <<= 1) cv += __shfl_xor(cv, m, 64);
      if (o == 0 && p < rem)
        lmap[(size_t)b*HW + s_pix[p]] = cv + (double)conv2_b[1];
    }
    __syncthreads();
  }
}

// ---------------- K7b: per-candidate score = sum_j exp64(lmap_j - m32) ----------------
__global__ __launch_bounds__(256) void score_kernel(const double* __restrict__ lmap,
                                                    const float* __restrict__ m32,
                                                    const int* __restrict__ cand_idx,
                                                    const int* __restrict__ cand_cnt,
                                                    double* __restrict__ cand_score,
                                                    int b0) {
  const int b = b0 + blockIdx.y;
  const int slot = blockIdx.x * 256 + threadIdx.x;
  if (slot >= cand_cnt[b]) return;
  const int idx = cand_idx[b*CAP + slot];
  const int ph = idx / WW, pw = idx % WW;
  const double m = (double)m32[b];
  double s = 0.0;
  for (int dy = -1; dy <= 1; dy++) {
    int qh = ph + dy;
    if (qh < 0 || qh >= HH) continue;
    for (int dx = -1; dx <= 1; dx++) {
      int qw = pw + dx;
      if (qw < 0 || qw >= WW) continue;
      s += exp(lmap[(size_t)b*HW + qh*WW + qw] - m);
    }
  }
  cand_score[b*CAP + slot] = s;
}

// ---------------- K8: sort 2048 candidates (score desc, idx asc) + emit ----------------
__global__ __launch_bounds__(1024) void emit_kernel(const double* __restrict__ cand_score,
                                                    const int* __restrict__ cand_idx,
                                                    const int* __restrict__ cand_cnt,
                                                    const float* __restrict__ depth,
                                                    float* __restrict__ points,
                                                    int b0) {
  const int b = b0 + blockIdx.x;
  const int tid = threadIdx.x;
  __shared__ double vals[CAP];
  __shared__ int    idxs[CAP];

  int cnt = cand_cnt[b];
  for (int i = tid; i < CAP; i += 1024) {
    if (i < cnt) { vals[i] = cand_score[b*CAP + i]; idxs[i] = cand_idx[b*CAP + i]; }
    else         { vals[i] = -1.0;                  idxs[i] = 0x7FFFFFFF; }
  }
  __syncthreads();

  for (unsigned k = 2; k <= CAP; k <<= 1) {
    for (unsigned j = k >> 1; j > 0; j >>= 1) {
      unsigned t = (unsigned)tid;           // one pair per thread (CAP/2 = 1024)
      unsigned i1 = ((t & ~(j - 1u)) << 1) | (t & (j - 1u));
      unsigned i2 = i1 | j;
      double v1 = vals[i1], v2 = vals[i2];
      int    a1 = idxs[i1], a2 = idxs[i2];
      bool oneAfterTwo = (v1 < v2) || (v1 == v2 && a1 > a2);
      bool descSeg = ((i1 & k) == 0);
      if (descSeg ? oneAfterTwo : !oneAfterTwo) {
        vals[i1] = v2; idxs[i1] = a2;
        vals[i2] = v1; idxs[i2] = a1;
      }
      __syncthreads();
    }
  }

  if (tid < KPTS) {
    int idx = idxs[tid];
    float d = depth[(size_t)b * HW + idx];
    float xi = (float)(idx % WW) / (float)WW;
    float yi = (float)(idx / WW) / (float)HH;
    float* pp = points + ((size_t)b * KPTS + tid) * 3;
    pp[0] = xi; pp[1] = yi; pp[2] = d;
  }
}

extern "C" void kernel_launch(void* const* d_in, const int* in_sizes, int n_in,
                              void* d_out, int out_size, void* d_ws, size_t ws_size,
                              hipStream_t stream) {
  const float* feat    = (const float*)d_in[0];
  const float* attn_w  = (const float*)d_in[1];
  const float* attn_b  = (const float*)d_in[2];
  const float* conv1_w = (const float*)d_in[3];
  const float* conv1_b = (const float*)d_in[4];
  const float* conv2_w = (const float*)d_in[5];
  const float* conv2_b = (const float*)d_in[6];

  float* out    = (float*)d_out;
  float* points = out;                          // 16*512*3
  float* depth  = out + 24576;                  // 16*36864
  float* conf_f = out + 24576 + BATCH*HW;       // 16*36864

  // ---- ws layout: doubles, floats, ushorts, ints, then xq region ----
  double* wsd        = (double*)d_ws;
  double* pool_d     = wsd;                                    // 2048
  double* attn_d     = wsd + 2048;                             // 2048
  double* cand_score = wsd + 4096;                             // 16*2048
  double* lmap       = cand_score + BATCH*CAP;                 // 16*36864
  double* wab64p     = lmap + (size_t)BATCH*HW;                // 16*128*64*10 (10.5 MB)
  double* psum       = wab64p + (size_t)BATCH*CIN*OC*10;       // 16*128*576 (9.4 MB)
  float*  wsf        = (float*)(psum + (size_t)BATCH*CIN*NXB);
  float*  logit32    = wsf;                                    // 589824
  float*  attn_f     = logit32 + (size_t)BATCH*HW;             // 2048
  float*  m32        = attn_f + 2048;                          // 16
  unsigned short* wb_h = (unsigned short*)(m32 + 16);          // 73728
  unsigned short* wb_l = wb_h + OC*CIN*9;                      // 73728
  int*    cand_idx   = (int*)(wb_l + OC*CIN*9);                // 16*2048
  int*    cand_cnt   = cand_idx + BATCH*CAP;                   // 16
  int*    upix       = cand_cnt + 16;                          // 16*18432
  int*    upix_cnt   = upix + BATCH*UMAX;                      // 16
  // xq region (256B aligned)
  size_t fixed_bytes = ((size_t)((char*)(upix_cnt + 16) - (char*)d_ws) + 255) & ~(size_t)255;
  char* dyn_base = (char*)d_ws + fixed_bytes;
  const size_t pbe = (size_t)HW * CIN;                         // elems per batch
  const size_t per_batch_bytes = pbe * 4;                      // xq only = 18.87 MB
  size_t avail = (ws_size > fixed_bytes + 65536) ? (ws_size - fixed_bytes - 65536) : 0;
  int gb = (int)(avail / per_batch_bytes);
  if (gb > BATCH) gb = BATCH;
  if (gb < 1) gb = 1;
  float* xq = (float*)dyn_base;

  wtrans_kernel<<<(OC*CIN*9 + 255)/256, 256, 0, stream>>>(conv1_w, wb_h, wb_l);

  for (int b0 = 0; b0 < BATCH; b0 += gb) {
    int g = (BATCH - b0 < gb) ? (BATCH - b0) : gb;
    xq_kernel<<<dim3(NXB, g), 256, 0, stream>>>(feat, xq, psum, b0);
    poolreduce_kernel<<<g*CIN, 64, 0, stream>>>(psum, pool_d, b0);
    attn_kernel<<<g, CIN, 0, stream>>>(pool_d, attn_w, attn_b, attn_d, attn_f, b0);
    wscale64_kernel<<<dim3((CIN*OC*10 + 255)/256, g), 256, 0, stream>>>(conv1_w, attn_d,
                                                                        wab64p, b0);
    conv_kernel<<<g*144, 256, 0, stream>>>(xq, attn_f, wb_h, wb_l,
                                           conv1_b, conv2_w, conv2_b,
                                           depth, logit32, b0, g*144);
    softmax_kernel<<<g, 1024, 0, stream>>>(logit32, m32, b0);
    box_kernel<<<(g*HW + 255)/256, 256, 0, stream>>>(logit32, conf_f, b0, g);
    cand_kernel<<<g, 1024, 0, stream>>>(conf_f, cand_idx, cand_cnt, upix, upix_cnt, b0);
    logit_kernel<<<g*LBLK, 256, 0, stream>>>(xq, wab64p, conv1_b, conv2_w, conv2_b,
                                             upix, upix_cnt, lmap, b0, g*LBLK);
    score_kernel<<<dim3(CAP/256, g), 256, 0, stream>>>(lmap, m32, cand_idx, cand_cnt,
                                                       cand_score, b0);
    emit_kernel<<<g, 1024, 0, stream>>>(cand_score, cand_idx, cand_cnt, depth, points, b0);
  }
}

// Round 23
// 946.927 us; speedup vs baseline: 1.3334x; 1.3334x over previous
//
#include <hip/hip_runtime.h>
#include <math.h>

#define BATCH 16
#define CIN   128
#define HH    192
#define WW    192
#define HW    (HH*WW)
#define OC    64
#define KPTS  512
#define CAP   2048
#define UMAX  (CAP*9)
#define LBLK  768     // logit slots per batch
#define PPB   8       // pixels per logit tile
#define NXB   (HW/64) // 576 xq blocks per batch

typedef short short8 __attribute__((ext_vector_type(8)));
typedef float f32x4 __attribute__((ext_vector_type(4)));

__device__ __forceinline__ unsigned short rne_bf16(float v) {
  unsigned u = __float_as_uint(v);
  u += 0x7FFFu + ((u >> 16) & 1u);
  return (unsigned short)(u >> 16);
}

// --- K1: transpose feat -> xq [bl][hw][c] raw f32 + per-block channel partial sums ---
__global__ __launch_bounds__(256) void xq_kernel(const float* __restrict__ feat,
                                                 float* __restrict__ xq,
                                                 double* __restrict__ psum,
                                                 int b0) {
  __shared__ float lds[64*130];                 // [px][c], pad 130
  const int bl = blockIdx.y;
  const int b  = b0 + bl;
  const int px0 = blockIdx.x * 64;
  const int tid = threadIdx.x;
  const int lane = tid & 63, wq = tid >> 6;

  #pragma unroll 8
  for (int k = 0; k < 32; k++) {
    int c = wq + 4*k;
    lds[lane*130 + c] = feat[((size_t)(b*CIN + c))*HW + px0 + lane];
  }
  __syncthreads();

  if (tid < CIN) {
    double s = 0.0;
    #pragma unroll 8
    for (int px = 0; px < 64; px++) s += (double)lds[px*130 + tid];
    psum[((size_t)b*CIN + tid)*NXB + blockIdx.x] = s;
  }

  const int px = tid >> 2, cq = tid & 3;
  size_t base = ((size_t)bl*HW + px0 + px)*CIN + cq*32;
  float4* xqp = (float4*)(xq + base);
  #pragma unroll
  for (int half = 0; half < 8; half++) {
    float4 q;
    #pragma unroll
    for (int j = 0; j < 4; j++)
      ((float*)&q)[j] = lds[px*130 + cq*32 + half*4 + j];
    xqp[half] = q;
  }
}

// --- K1b: reduce psum -> pool (f64, fixed order) ---
__global__ __launch_bounds__(64) void poolreduce_kernel(const double* __restrict__ psum,
                                                        double* __restrict__ pool,
                                                        int b0) {
  const int lb = blockIdx.x / CIN, c = blockIdx.x % CIN;
  const int b = b0 + lb;
  const int tid = threadIdx.x;
  const double* pp = psum + ((size_t)b*CIN + c)*NXB;
  double s = 0.0;
  for (int j = tid; j < NXB; j += 64) s += pp[j];
  for (int off = 32; off > 0; off >>= 1) s += __shfl_down(s, off, 64);
  if (tid == 0) pool[b*CIN + c] = s / 36864.0;
}

// ---------------- K2: attn = sigmoid(pool @ attn_w.T + attn_b) ----------------
__global__ __launch_bounds__(128) void attn_kernel(const double* __restrict__ pool,
                                                   const float* __restrict__ attn_w,
                                                   const float* __restrict__ attn_b,
                                                   double* __restrict__ attn_d,
                                                   float* __restrict__ attn_f,
                                                   int b0) {
  __shared__ double sp[CIN];
  int b = b0 + blockIdx.x, c = threadIdx.x;
  sp[c] = pool[b*CIN + c];
  __syncthreads();
  double s = (double)attn_b[c];
  const float* wr = attn_w + (size_t)c * CIN;
  for (int j = 0; j < CIN; j++) s = fma((double)wr[j], sp[j], s);
  double a = 1.0 / (1.0 + exp(-s));
  attn_d[b*CIN + c] = a;
  attn_f[b*CIN + c] = (float)a;
}

// --- K2b: shared split-bf16 wb [tap][oc][c] for the conv ---
__global__ __launch_bounds__(256) void wtrans_kernel(const float* __restrict__ w,
                                                     unsigned short* __restrict__ wb_h,
                                                     unsigned short* __restrict__ wb_l) {
  int i = blockIdx.x * 256 + threadIdx.x;
  if (i < OC*CIN*9) {
    int oc = i / (CIN*9);
    int r  = i % (CIN*9);
    int c  = r / 9;
    int k  = r % 9;
    float v = w[i];
    unsigned short h = rne_bf16(v);
    float hf = __uint_as_float((unsigned)h << 16);
    wb_h[((size_t)k*OC + oc)*CIN + c] = h;
    wb_l[((size_t)k*OC + oc)*CIN + c] = rne_bf16(v - hf);
  }
}

// --- K2c: per-batch f64 attn-folded refine weights wab64p[b][c][oc][10] (pad=0) ---
__global__ __launch_bounds__(256) void wscale64_kernel(const float* __restrict__ w,
                                                       const double* __restrict__ attn_d,
                                                       double* __restrict__ wab64p,
                                                       int b0) {
  const int b = b0 + blockIdx.y;
  int i = blockIdx.x * 256 + threadIdx.x;   // i over CIN*OC*10
  if (i < CIN*OC*10) {
    int kk = i % 10;
    int co = i / 10;
    int oc = co & 63, c = co >> 6;
    double v = 0.0;
    if (kk < 9) v = (double)w[((size_t)oc*CIN + c)*9 + kk] * attn_d[b*CIN + c];
    wab64p[(((size_t)b*CIN + c)*OC + oc)*10 + kk] = v;
  }
}

// -------- K3: split-bf16 MFMA conv; stage from xq (raw f32) with in-stage attn+split --------
#define TLH 18
#define TLW 18
#define CST 36
__global__ __launch_bounds__(256, 3) void conv_kernel(const float* __restrict__ xq,
                                                      const float* __restrict__ attn_f,
                                                      const unsigned short* __restrict__ wb_h,
                                                      const unsigned short* __restrict__ wb_l,
                                                      const float* __restrict__ conv1_b,
                                                      const float* __restrict__ conv2_w,
                                                      const float* __restrict__ conv2_b,
                                                      float* __restrict__ depth_out,
                                                      float* __restrict__ logit_out,
                                                      int b0, int nwg) {
  // bijective XCD swizzle (m204): nwg = g*144
  int bid = blockIdx.x;
  int q = nwg >> 3, r = nwg & 7;
  int xcd = bid & 7, pos = bid >> 3;
  int swz = (xcd < r ? xcd*(q+1) : r*(q+1) + (xcd - r)*q) + pos;
  const int bl = swz / 144;
  const int t144 = swz % 144;
  const int b  = b0 + bl;
  const int h0 = (t144 / 12) * 16, w0 = (t144 % 12) * 16;
  const int tid = threadIdx.x;
  const int wv = tid >> 6, ln = tid & 63;
  const int lg = ln >> 4, lr = ln & 15;

  __shared__ __align__(16) unsigned short th[TLH*TLW*CST];  // 23328 B
  __shared__ __align__(16) unsigned short tl[TLH*TLW*CST];  // 23328 B
  __shared__ float s_attn[CIN];

  if (tid < CIN) s_attn[tid] = attn_f[b*CIN + tid];

  f32x4 acc[4][4];
  #pragma unroll
  for (int mi = 0; mi < 4; mi++)
    #pragma unroll
    for (int ni = 0; ni < 4; ni++)
      acc[mi][ni] = (f32x4){0.f, 0.f, 0.f, 0.f};

  const short8 zero8 = (short8){0,0,0,0,0,0,0,0};

  #pragma unroll 1
  for (int c0 = 0; c0 < CIN; c0 += 32) {
    __syncthreads();
    for (int i = tid; i < TLH*TLW*4; i += 256) {
      int rr  = i / (TLW*4);
      int rw  = i % (TLW*4);
      int col = rw >> 2, sub = rw & 3;
      int gh = h0 + rr - 1, gw = w0 + col - 1;
      short8 hv = zero8, lv = zero8;
      if (gh >= 0 && gh < HH && gw >= 0 && gw < WW) {
        const float4* src = (const float4*)(xq
            + ((size_t)(bl*HH + gh)*WW + gw)*CIN + c0 + sub*8);
        float4 f0 = src[0], f1 = src[1];
        #pragma unroll
        for (int j = 0; j < 8; j++) {
          float raw = (j < 4) ? ((const float*)&f0)[j] : ((const float*)&f1)[j-4];
          float v = raw * s_attn[c0 + sub*8 + j];
          unsigned short h = rne_bf16(v);
          hv[j] = (short)h;
          lv[j] = (short)rne_bf16(v - __uint_as_float((unsigned)h << 16));
        }
      }
      int off = (rr*TLW + col)*CST + sub*8;
      *reinterpret_cast<short8*>(&th[off]) = hv;
      *reinterpret_cast<short8*>(&tl[off]) = lv;
    }
    __syncthreads();

    #pragma unroll
    for (int v = 0; v < 3; v++) {
      short8 ah[6], al[6];
      #pragma unroll
      for (int r6 = 0; r6 < 6; r6++) {
        int off = ((4*wv + r6)*TLW + lr + v)*CST + 8*lg;
        ah[r6] = *reinterpret_cast<const short8*>(&th[off]);
        al[r6] = *reinterpret_cast<const short8*>(&tl[off]);
      }
      #pragma unroll
      for (int u = 0; u < 3; u++) {
        short8 bh[4], blo[4];
        #pragma unroll
        for (int ni = 0; ni < 4; ni++) {
          size_t woff = ((size_t)(u*3 + v)*OC + ni*16 + lr)*CIN + c0 + 8*lg;
          bh[ni]  = *reinterpret_cast<const short8*>(wb_h + woff);
          blo[ni] = *reinterpret_cast<const short8*>(wb_l + woff);
        }
        #pragma unroll
        for (int mi = 0; mi < 4; mi++) {
          #pragma unroll
          for (int ni = 0; ni < 4; ni++) {
            acc[mi][ni] = __builtin_amdgcn_mfma_f32_16x16x32_bf16(ah[mi+u], bh[ni],  acc[mi][ni], 0, 0, 0);
            acc[mi][ni] = __builtin_amdgcn_mfma_f32_16x16x32_bf16(ah[mi+u], blo[ni], acc[mi][ni], 0, 0, 0);
            acc[mi][ni] = __builtin_amdgcn_mfma_f32_16x16x32_bf16(al[mi+u], bh[ni],  acc[mi][ni], 0, 0, 0);
          }
        }
      }
    }
  }

  float bia[4], w20[4], w21[4];
  #pragma unroll
  for (int ni = 0; ni < 4; ni++) {
    int oc = ni*16 + lr;
    bia[ni] = conv1_b[oc];
    w20[ni] = conv2_w[oc];
    w21[ni] = conv2_w[OC + oc];
  }
  const float c2b0 = conv2_b[0], c2b1 = conv2_b[1];

  #pragma unroll
  for (int mi = 0; mi < 4; mi++) {
    const int gh = h0 + 4*wv + mi;
    #pragma unroll
    for (int q2 = 0; q2 < 4; q2++) {
      float s0 = 0.f, s1 = 0.f;
      #pragma unroll
      for (int ni = 0; ni < 4; ni++) {
        float z = acc[mi][ni][q2] + bia[ni];
        float g = 0.5f * z * (1.0f + erff(z * 0.70710678118654752f));
        s0 = fmaf(g, w20[ni], s0);
        s1 = fmaf(g, w21[ni], s1);
      }
      #pragma unroll
      for (int m = 1; m <= 8; m <<= 1) {
        s0 += __shfl_xor(s0, m, 64);
        s1 += __shfl_xor(s1, m, 64);
      }
      if (lr == 0) {
        const int gw = w0 + 4*lg + q2;
        depth_out[((size_t)b*HH + gh)*WW + gw] = s0 + c2b0;
        logit_out[((size_t)b*HH + gh)*WW + gw] = s1 + c2b1;
      }
    }
  }
}

// ---------------- K4: per-batch softmax over HW (fp32, in place) + save max ----------------
__global__ __launch_bounds__(1024) void softmax_kernel(float* __restrict__ logits,
                                                       float* __restrict__ m_out,
                                                       int b0) {
  const int b = b0 + blockIdx.x;
  float* lp = logits + (size_t)b * HW;
  const int tid = threadIdx.x;
  __shared__ float sred[16];
  __shared__ float s_m, s_z;

  float m = -INFINITY;
  for (int i = tid; i < HW; i += 1024) m = fmaxf(m, lp[i]);
  for (int off = 32; off > 0; off >>= 1) m = fmaxf(m, __shfl_down(m, off, 64));
  if ((tid & 63) == 0) sred[tid >> 6] = m;
  __syncthreads();
  if (tid == 0) {
    float t = sred[0];
    for (int i = 1; i < 16; i++) t = fmaxf(t, sred[i]);
    s_m = t;
    m_out[b] = t;
  }
  __syncthreads();
  m = s_m;

  float z = 0.f;
  for (int i = tid; i < HW; i += 1024) z += expf(lp[i] - m);
  __syncthreads();
  for (int off = 32; off > 0; off >>= 1) z += __shfl_down(z, off, 64);
  if ((tid & 63) == 0) sred[tid >> 6] = z;
  __syncthreads();
  if (tid == 0) {
    float t = 0.f;
    for (int i = 0; i < 16; i++) t += sred[i];
    s_z = t;
  }
  __syncthreads();
  z = s_z;

  for (int i = tid; i < HW; i += 1024) lp[i] = expf(lp[i] - m) / z;
}

// ---------------- K5: 3x3 box filter (zero pad) / 9, fp32 ----------------
__global__ __launch_bounds__(256) void box_kernel(const float* __restrict__ p,
                                                  float* __restrict__ out_f,
                                                  int b0, int g) {
  int i = blockIdx.x * 256 + threadIdx.x;
  if (i >= g * HW) return;
  int b = b0 + i / HW, r = i % HW, h = r / WW, w = r % WW;
  const float* bp = p + (size_t)b * HW;
  float s = 0.f;
  for (int dy = -1; dy <= 1; dy++) {
    int h2 = h + dy;
    if (h2 < 0 || h2 >= HH) continue;
    for (int dx = -1; dx <= 1; dx++) {
      int w2 = w + dx;
      if (w2 < 0 || w2 >= WW) continue;
      s += bp[h2*WW + w2];
    }
  }
  out_f[(size_t)b*HW + r] = s / 9.0f;
}

// ---------------- K6: candidates (margin 1e-4) + union-of-neighborhood list ----------------
__global__ __launch_bounds__(1024) void cand_kernel(const float* __restrict__ conf,
                                                    int* __restrict__ cand_idx,
                                                    int* __restrict__ cand_cnt,
                                                    int* __restrict__ upix,
                                                    int* __restrict__ upix_cnt,
                                                    int b0) {
  const int b = b0 + blockIdx.x;
  const float* cp = conf + (size_t)b * HW;
  const int tid = threadIdx.x;
  __shared__ unsigned sred[16];
  __shared__ unsigned s_total;
  __shared__ unsigned s_cnt;
  __shared__ unsigned bm[1152];     // 36864-bit map
  __shared__ unsigned pcs[1152];
  __shared__ unsigned grpoff[37];

  unsigned lo = 0u, hi = 0x7F800000u;   // conf > 0 always
  while (hi - lo > 1u) {
    unsigned mid = lo + ((hi - lo) >> 1);
    unsigned cnt = 0;
    for (int i = tid; i < HW; i += 1024)
      cnt += (__float_as_uint(cp[i]) >= mid) ? 1u : 0u;
    for (int off = 32; off > 0; off >>= 1) cnt += __shfl_down(cnt, off, 64);
    if ((tid & 63) == 0) sred[tid >> 6] = cnt;
    __syncthreads();
    if (tid == 0) {
      unsigned t = 0;
      for (int i = 0; i < 16; i++) t += sred[i];
      s_total = t;
    }
    __syncthreads();
    unsigned total = s_total;
    __syncthreads();
    if (total >= KPTS) lo = mid; else hi = mid;
  }
  float vcut = __uint_as_float(lo) * (1.0f - 1e-4f);  // fp32-path conf err ~2e-6 rel

  if (tid == 0) s_cnt = 0;
  for (int i = tid; i < 1152; i += 1024) bm[i] = 0u;
  __syncthreads();

  for (int i = tid; i < HW; i += 1024) {
    if (cp[i] >= vcut) {
      unsigned s = atomicAdd(&s_cnt, 1u);
      if (s < CAP) {
        cand_idx[b*CAP + s] = i;
        int h = i / WW, w = i % WW;
        for (int dy = -1; dy <= 1; dy++) {
          int qh = h + dy;
          if (qh < 0 || qh >= HH) continue;
          for (int dx = -1; dx <= 1; dx++) {
            int qw = w + dx;
            if (qw < 0 || qw >= WW) continue;
            int q = qh*WW + qw;
            atomicOr(&bm[q >> 5], 1u << (q & 31));
          }
        }
      }
    }
  }
  __syncthreads();
  if (tid == 0) cand_cnt[b] = (s_cnt < CAP) ? s_cnt : CAP;

  for (int i = tid; i < 1152; i += 1024) pcs[i] = __popc(bm[i]);
  __syncthreads();
  if (tid < 36) {
    unsigned s = 0;
    for (int j = 0; j < 32; j++) s += pcs[tid*32 + j];
    grpoff[tid] = s;
  }
  __syncthreads();
  if (tid == 0) {
    unsigned run = 0;
    for (int g2 = 0; g2 < 36; g2++) { unsigned t = grpoff[g2]; grpoff[g2] = run; run += t; }
    grpoff[36] = run;
    upix_cnt[b] = (int)run;
  }
  __syncthreads();
  for (int i = tid; i < 1152; i += 1024) {
    unsigned off = grpoff[i >> 5];
    for (int w = (i & ~31); w < i; w++) off += pcs[w];
    unsigned u = bm[i];
    while (u) {
      int bit = __ffs(u) - 1;
      u &= u - 1u;
      upix[b*UMAX + off++] = i*32 + bit;
    }
  }
}

// ------- K7a: f64 logit; PPB=8/tile; x gathered from xq (channel-fastest, coalesced) -------
__global__ __launch_bounds__(256) void logit_kernel(const float* __restrict__ xq,
                                                    const double* __restrict__ wab64p,
                                                    const float* __restrict__ conv1_b,
                                                    const float* __restrict__ conv2_w,
                                                    const float* __restrict__ conv2_b,
                                                    const int* __restrict__ upix,
                                                    const int* __restrict__ upix_cnt,
                                                    double* __restrict__ lmap,
                                                    int b0, int nb) {
  // bijective chunked XCD swizzle (nb = g*LBLK, % 8 == 0)
  int bid = blockIdx.x;
  int swz = (bid & 7) * (nb >> 3) + (bid >> 3);
  const int bl = swz / LBLK;            // local batch in group
  const int b  = b0 + bl;
  const int slot0 = swz % LBLK;
  const int ucnt = upix_cnt[b];
  const int tid = threadIdx.x;

  __shared__ __align__(16) float xf[PPB][1536];   // 48 KB : f32 x, channel stride 12
  __shared__ double part[4][PPB][64];             // 16 KB  [cq][p][oc]
  __shared__ int    s_pix[PPB];

  for (int base = slot0*PPB; base < ucnt; base += LBLK*PPB) {
    const int rem = min(PPB, ucnt - base);
    if (tid < PPB) s_pix[tid] = (tid < rem) ? upix[b*UMAX + base + tid] : 0;
    __syncthreads();

    for (int i = tid; i < PPB*9*32; i += 256) {
      int p = i / 288;
      int r = i % 288;
      int k = r >> 5, t = r & 31;
      float4 v = (float4){0.f, 0.f, 0.f, 0.f};
      if (p < rem) {
        int pix = s_pix[p];
        int gh = pix / WW + k/3 - 1, gw = pix % WW + k%3 - 1;
        if (gh >= 0 && gh < HH && gw >= 0 && gw < WW)
          v = *reinterpret_cast<const float4*>(
                xq + ((size_t)(bl*HW + gh*WW + gw))*CIN + 4*t);
      }
      int cb = 4*t;
      xf[p][(cb+0)*12 + k] = v.x;
      xf[p][(cb+1)*12 + k] = v.y;
      xf[p][(cb+2)*12 + k] = v.z;
      xf[p][(cb+3)*12 + k] = v.w;
    }
    __syncthreads();

    const int oc = tid & 63, cq = tid >> 6;
    double acc[PPB];
    #pragma unroll
    for (int p = 0; p < PPB; p++) acc[p] = 0.0;
    const double* wp = wab64p + (((size_t)b*CIN + cq*32)*OC + oc)*10;
    for (int cc = 0; cc < 32; cc++) {
      const int c = cq*32 + cc;
      double2 wv[5];
      #pragma unroll
      for (int q = 0; q < 5; q++) wv[q] = *((const double2*)wp + q);
      wp += OC*10;
      #pragma unroll
      for (int p = 0; p < PPB; p++) {
        const float4* xp = (const float4*)&xf[p][c*12];
        float4 a = xp[0], bb = xp[1], cc4 = xp[2];
        double t = acc[p];
        t = fma(wv[0].x, (double)a.x,  t);
        t = fma(wv[0].y, (double)a.y,  t);
        t = fma(wv[1].x, (double)a.z,  t);
        t = fma(wv[1].y, (double)a.w,  t);
        t = fma(wv[2].x, (double)bb.x, t);
        t = fma(wv[2].y, (double)bb.y, t);
        t = fma(wv[3].x, (double)bb.z, t);
        t = fma(wv[3].y, (double)bb.w, t);
        t = fma(wv[4].x, (double)cc4.x, t);
        acc[p] = t;
      }
    }
    #pragma unroll
    for (int p = 0; p < PPB; p++) part[cq][p][oc] = acc[p];
    __syncthreads();

    for (int t0 = tid; t0 < PPB*64; t0 += 256) {
      const int p = t0 >> 6, o = t0 & 63;
      double z = part[0][p][o] + part[1][p][o] + part[2][p][o] + part[3][p][o]
               + (double)conv1_b[o];
      double g = 0.5 * z * (1.0 + erf(z * 0.70710678118654752440));
      double cv = g * (double)conv2_w[OC + o];
      #pragma unroll
      for (int m = 1; m <= 32; m <<= 1) cv += __shfl_xor(cv, m, 64);
      if (o == 0 && p < rem)
        lmap[(size_t)b*HW + s_pix[p]] = cv + (double)conv2_b[1];
    }
    __syncthreads();
  }
}

// ---------------- K7b: per-candidate score = sum_j exp64(lmap_j - m32) ----------------
__global__ __launch_bounds__(256) void score_kernel(const double* __restrict__ lmap,
                                                    const float* __restrict__ m32,
                                                    const int* __restrict__ cand_idx,
                                                    const int* __restrict__ cand_cnt,
                                                    double* __restrict__ cand_score,
                                                    int b0) {
  const int b = b0 + blockIdx.y;
  const int slot = blockIdx.x * 256 + threadIdx.x;
  if (slot >= cand_cnt[b]) return;
  const int idx = cand_idx[b*CAP + slot];
  const int ph = idx / WW, pw = idx % WW;
  const double m = (double)m32[b];
  double s = 0.0;
  for (int dy = -1; dy <= 1; dy++) {
    int qh = ph + dy;
    if (qh < 0 || qh >= HH) continue;
    for (int dx = -1; dx <= 1; dx++) {
      int qw = pw + dx;
      if (qw < 0 || qw >= WW) continue;
      s += exp(lmap[(size_t)b*HW + qh*WW + qw] - m);
    }
  }
  cand_score[b*CAP + slot] = s;
}

// ---------------- K8: sort 2048 candidates (score desc, idx asc) + emit ----------------
__global__ __launch_bounds__(1024) void emit_kernel(const double* __restrict__ cand_score,
                                                    const int* __restrict__ cand_idx,
                                                    const int* __restrict__ cand_cnt,
                                                    const float* __restrict__ depth,
                                                    float* __restrict__ points,
                                                    int b0) {
  const int b = b0 + blockIdx.x;
  const int tid = threadIdx.x;
  __shared__ double vals[CAP];
  __shared__ int    idxs[CAP];

  int cnt = cand_cnt[b];
  for (int i = tid; i < CAP; i += 1024) {
    if (i < cnt) { vals[i] = cand_score[b*CAP + i]; idxs[i] = cand_idx[b*CAP + i]; }
    else         { vals[i] = -1.0;                  idxs[i] = 0x7FFFFFFF; }
  }
  __syncthreads();

  for (unsigned k = 2; k <= CAP; k <<= 1) {
    for (unsigned j = k >> 1; j > 0; j >>= 1) {
      unsigned t = (unsigned)tid;           // one pair per thread (CAP/2 = 1024)
      unsigned i1 = ((t & ~(j - 1u)) << 1) | (t & (j - 1u));
      unsigned i2 = i1 | j;
      double v1 = vals[i1], v2 = vals[i2];
      int    a1 = idxs[i1], a2 = idxs[i2];
      bool oneAfterTwo = (v1 < v2) || (v1 == v2 && a1 > a2);
      bool descSeg = ((i1 & k) == 0);
      if (descSeg ? oneAfterTwo : !oneAfterTwo) {
        vals[i1] = v2; idxs[i1] = a2;
        vals[i2] = v1; idxs[i2] = a1;
      }
      __syncthreads();
    }
  }

  if (tid < KPTS) {
    int idx = idxs[tid];
    float d = depth[(size_t)b * HW + idx];
    float xi = (float)(idx % WW) / (float)WW;
    float yi = (float)(idx / WW) / (float)HH;
    float* pp = points + ((size_t)b * KPTS + tid) * 3;
    pp[0] = xi; pp[1] = yi; pp[2] = d;
  }
}

extern "C" void kernel_launch(void* const* d_in, const int* in_sizes, int n_in,
                              void* d_out, int out_size, void* d_ws, size_t ws_size,
                              hipStream_t stream) {
  const float* feat    = (const float*)d_in[0];
  const float* attn_w  = (const float*)d_in[1];
  const float* attn_b  = (const float*)d_in[2];
  const float* conv1_w = (const float*)d_in[3];
  const float* conv1_b = (const float*)d_in[4];
  const float* conv2_w = (const float*)d_in[5];
  const float* conv2_b = (const float*)d_in[6];

  float* out    = (float*)d_out;
  float* points = out;                          // 16*512*3
  float* depth  = out + 24576;                  // 16*36864
  float* conf_f = out + 24576 + BATCH*HW;       // 16*36864

  // ---- ws layout: doubles, floats, ushorts, ints, then xq region ----
  double* wsd        = (double*)d_ws;
  double* pool_d     = wsd;                                    // 2048
  double* attn_d     = wsd + 2048;                             // 2048
  double* cand_score = wsd + 4096;                             // 16*2048
  double* lmap       = cand_score + BATCH*CAP;                 // 16*36864
  double* wab64p     = lmap + (size_t)BATCH*HW;                // 16*128*64*10 (10.5 MB)
  double* psum       = wab64p + (size_t)BATCH*CIN*OC*10;       // 16*128*576 (9.4 MB)
  float*  wsf        = (float*)(psum + (size_t)BATCH*CIN*NXB);
  float*  logit32    = wsf;                                    // 589824
  float*  attn_f     = logit32 + (size_t)BATCH*HW;             // 2048
  float*  m32        = attn_f + 2048;                          // 16
  unsigned short* wb_h = (unsigned short*)(m32 + 16);          // 73728
  unsigned short* wb_l = wb_h + OC*CIN*9;                      // 73728
  int*    cand_idx   = (int*)(wb_l + OC*CIN*9);                // 16*2048
  int*    cand_cnt   = cand_idx + BATCH*CAP;                   // 16
  int*    upix       = cand_cnt + 16;                          // 16*18432
  int*    upix_cnt   = upix + BATCH*UMAX;                      // 16
  // xq region (256B aligned)
  size_t fixed_bytes = ((size_t)((char*)(upix_cnt + 16) - (char*)d_ws) + 255) & ~(size_t)255;
  char* dyn_base = (char*)d_ws + fixed_bytes;
  const size_t pbe = (size_t)HW * CIN;                         // elems per batch
  const size_t per_batch_bytes = pbe * 4;                      // xq only = 18.87 MB
  size_t avail = (ws_size > fixed_bytes + 65536) ? (ws_size - fixed_bytes - 65536) : 0;
  int gb = (int)(avail / per_batch_bytes);
  if (gb > BATCH) gb = BATCH;
  if (gb < 1) gb = 1;
  float* xq = (float*)dyn_base;

  wtrans_kernel<<<(OC*CIN*9 + 255)/256, 256, 0, stream>>>(conv1_w, wb_h, wb_l);

  for (int b0 = 0; b0 < BATCH; b0 += gb) {
    int g = (BATCH - b0 < gb) ? (BATCH - b0) : gb;
    xq_kernel<<<dim3(NXB, g), 256, 0, stream>>>(feat, xq, psum, b0);
    poolreduce_kernel<<<g*CIN, 64, 0, stream>>>(psum, pool_d, b0);
    attn_kernel<<<g, CIN, 0, stream>>>(pool_d, attn_w, attn_b, attn_d, attn_f, b0);
    wscale64_kernel<<<dim3((CIN*OC*10 + 255)/256, g), 256, 0, stream>>>(conv1_w, attn_d,
                                                                        wab64p, b0);
    conv_kernel<<<g*144, 256, 0, stream>>>(xq, attn_f, wb_h, wb_l,
                                           conv1_b, conv2_w, conv2_b,
                                           depth, logit32, b0, g*144);
    softmax_kernel<<<g, 1024, 0, stream>>>(logit32, m32, b0);
    box_kernel<<<(g*HW + 255)/256, 256, 0, stream>>>(logit32, conf_f, b0, g);
    cand_kernel<<<g, 1024, 0, stream>>>(conf_f, cand_idx, cand_cnt, upix, upix_cnt, b0);
    logit_kernel<<<g*LBLK, 256, 0, stream>>>(xq, wab64p, conv1_b, conv2_w, conv2_b,
                                             upix, upix_cnt, lmap, b0, g*LBLK);
    score_kernel<<<dim3(CAP/256, g), 256, 0, stream>>>(lmap, m32, cand_idx, cand_cnt,
                                                       cand_score, b0);
    emit_kernel<<<g, 1024, 0, stream>>>(cand_score, cand_idx, cand_cnt, depth, points, b0);
  }
}